// Round 8
// baseline (166.822 us; speedup 1.0000x reference)
//
#include <hip/hip_runtime.h>
#include <math.h>

#define NROWS 8192
#define KDIM  768            // elements per row; for i8 buffers this is also BYTES
#define BM 128
#define BN 128
#define BKB 128              // K-tile bytes per row (128 i8 = 2 MFMA k-steps of 64)
#define KTILES (KDIM / BKB)  // 6
#define NBC 2                // bc tiles swept per block
#define NBCG (NROWS / BN / NBC)  // 32 -> grid 64*32 = 2048 blocks = 5/CU (LDS-capped)

typedef int i32x4 __attribute__((ext_vector_type(4)));  // i8 MFMA A/B frag (16 bytes) and C/D

// monotonic float<->uint encoding so atomicMax(uint) == float max
static __device__ __forceinline__ unsigned enc_f(float f) {
    unsigned x = __float_as_uint(f);
    return (x & 0x80000000u) ? ~x : (x | 0x80000000u);
}
static __device__ __forceinline__ float dec_f(unsigned u) {
    unsigned x = (u & 0x80000000u) ? (u ^ 0x80000000u) : ~u;
    return __uint_as_float(x);
}

// one wave per row: fp32 normalize (exact), then symmetric int8 quantization
// with per-row scale amax/127. blocks 0..31 also init the out buffer.
__global__ __launch_bounds__(256) void normalize_quant_k(
        const float* __restrict__ ex, const float* __restrict__ ey,
        signed char* __restrict__ q, float* __restrict__ scales,
        unsigned* __restrict__ out) {
    if (blockIdx.x < NROWS / 256)
        out[blockIdx.x * 256 + threadIdx.x] = enc_f(-INFINITY);
    const int wave = threadIdx.x >> 6, lane = threadIdx.x & 63;
    const int grow = blockIdx.x * 4 + wave;          // 0..16383
    const float* src = (grow < NROWS) ? ex : ey;
    const int row = grow & (NROWS - 1);
    const float4* xr = (const float4*)(src + (size_t)row * KDIM);  // 192 float4
    float4 v[3];
    #pragma unroll
    for (int g = 0; g < 3; ++g) v[g] = xr[lane + g * 64];
    float ss = 0.f, am = 0.f;
    #pragma unroll
    for (int g = 0; g < 3; ++g) {
        ss += v[g].x * v[g].x + v[g].y * v[g].y + v[g].z * v[g].z + v[g].w * v[g].w;
        am = fmaxf(am, fmaxf(fmaxf(fabsf(v[g].x), fabsf(v[g].y)),
                             fmaxf(fabsf(v[g].z), fabsf(v[g].w))));
    }
    #pragma unroll
    for (int off = 32; off > 0; off >>= 1) {
        ss += __shfl_xor(ss, off);
        am = fmaxf(am, __shfl_xor(am, off));
    }
    const float scale = 1.0f / fmaxf(sqrtf(ss), 1e-8f);
    am = fmaxf(am * scale, 1e-12f);        // amax of the NORMALIZED row
    if (lane == 0) scales[grow] = am * (1.0f / 127.0f);
    const float si = scale * (127.0f / am);            // raw -> int8 code
    int* dr = (int*)(q + (size_t)grow * KDIM);         // 192 packed ints / row
    #pragma unroll
    for (int g = 0; g < 3; ++g) {
        int qx = min(127, max(-127, __float2int_rn(v[g].x * si)));
        int qy = min(127, max(-127, __float2int_rn(v[g].y * si)));
        int qz = min(127, max(-127, __float2int_rn(v[g].z * si)));
        int qw = min(127, max(-127, __float2int_rn(v[g].w * si)));
        dr[lane + g * 64] = (qx & 0xff) | ((qy & 0xff) << 8) |
                            ((qz & 0xff) << 16) | ((qw & 0xff) << 24);
    }
}

// R4 internals unchanged (128^2 tile, 4 waves, chunk-XOR swizzle, 0 conflicts,
// 2-sync loop — best measured staging rate). Concurrency upgrade:
// NBC 4->2 => grid 2048 blocks => 5 blocks/CU (LDS-capped at 32 KB each).
// Mechanism (R4/R5/R6/R7 rate law): global->LDS ingest rate per CU scales
// with outstanding staging windows (R4 4x32KB: 16.5 B/cy; R7 2x48KB: 12.7;
// R6 4x16KB: ~10). Volume is invariant under NBC change (A-redundancy halves,
// B-block-count doubles: 805 MB either way); +25% windows -> +~20% rate.
// XCD rectangle: 16 br x 16 bcg per XCD -> A 1.57 MB + B 32bc x 98KB = 4.7 MB
// ~= L2 (the R4-proven working-set size). Bijective decode.
// Epilogue hoisted out of the bi-loop: running per-(mi,r) max in registers,
// one shfl-tree + atomic per wave at the end (halves epilogue VALU/atomics).
__global__ __launch_bounds__(256, 5) void gemm_rowmax_i8_k(
        const signed char* __restrict__ A, const signed char* __restrict__ B,
        const float* __restrict__ sa, const float* __restrict__ sb,
        unsigned* __restrict__ out) {
    __shared__ signed char As[BM * BKB];   // 16 KB
    __shared__ signed char Bs[BN * BKB];   // 16 KB

    const int tid  = threadIdx.x;
    const int wave = tid >> 6, lane = tid & 63;
    // 2D XCD-aware decode (speed-only heuristic; correctness independent)
    const int xcd = blockIdx.x & 7;        // dispatch round-robins XCDs
    const int idx = blockIdx.x >> 3;       // 0..255 within XCD
    const int br  = (xcd >> 1) * 16 + (idx & 15);   // 0..63
    const int bcg = (xcd & 1) * 16 + (idx >> 4);    // 0..31

    // staging: wave issue = 8 rows x 128 B; slot s of row r holds chunk s^(r&7)
    const int srow   = lane >> 3;
    const int gchunk = (lane & 7) ^ srow;
    const int scol   = gchunk * 16;        // bytes
    // issue i covers rows (wave+4i)*8+srow -> global byte offset i*24576 from base
    const signed char* aStage = A + (size_t)(br * BM + wave * 8 + srow) * KDIM + scol;
    signed char* lA = As + wave * 1024;    // + i*4096
    signed char* lB = Bs + wave * 1024;

    // compute geometry: wave 64x64, 4x4 tiles of 16x16x64
    const int wm = (wave >> 1) * 64, wn = (wave & 1) * 64;
    const int quad = lane >> 4, mrow = lane & 15;
    const int c0 = quad ^ (mrow & 7);      // swizzled chunk slot; ks=1: ^4
    const signed char* aBase = As + (wm + mrow) * BKB;
    const signed char* bBase = Bs + (wn + mrow) * BKB;
    const int row0 = br * BM + wm + quad * 4;

    // running row-max across the whole bc sweep (epilogue hoisted)
    float rm[4][4];
    #pragma unroll
    for (int mi = 0; mi < 4; ++mi)
        #pragma unroll
        for (int r = 0; r < 4; ++r) rm[mi][r] = -INFINITY;

    #pragma unroll 1
    for (int bi = 0; bi < NBC; ++bi) {
        const int bc = bcg * NBC + bi;
        const signed char* bStage =
            B + (size_t)(bc * BN + wave * 8 + srow) * KDIM + scol;

        i32x4 acc[4][4] = {};

        #pragma unroll 1
        for (int kt = 0; kt < KTILES; ++kt) {
            __syncthreads();   // previous tile's LDS reads done
            #pragma unroll
            for (int i = 0; i < 4; ++i) {
                __builtin_amdgcn_global_load_lds(
                    (const __attribute__((address_space(1))) void*)(aStage + kt * BKB + i * 24576),
                    (__attribute__((address_space(3))) void*)(lA + i * 4096), 16, 0, 0);
                __builtin_amdgcn_global_load_lds(
                    (const __attribute__((address_space(1))) void*)(bStage + kt * BKB + i * 24576),
                    (__attribute__((address_space(3))) void*)(lB + i * 4096), 16, 0, 0);
            }
            __syncthreads();   // staging complete

            #pragma unroll 1
            for (int ks = 0; ks < 2; ++ks) {
                const int ck = c0 ^ (ks << 2);
                i32x4 af[4], bfr[4];
                #pragma unroll
                for (int mi = 0; mi < 4; ++mi)
                    af[mi] = *(const i32x4*)(aBase + mi * 16 * BKB + ck * 16);
                #pragma unroll
                for (int ni = 0; ni < 4; ++ni)
                    bfr[ni] = *(const i32x4*)(bBase + ni * 16 * BKB + ck * 16);
                #pragma unroll
                for (int mi = 0; mi < 4; ++mi)
                    #pragma unroll
                    for (int ni = 0; ni < 4; ++ni)
                        acc[mi][ni] = __builtin_amdgcn_mfma_i32_16x16x64_i8(
                            af[mi], bfr[ni], acc[mi][ni], 0, 0, 0);
            }
        }

        // fold sb[col] per ni (col = lane&15 within each 16-tile) and keep a
        // running in-register max; cross-lane reduction deferred to the end.
        float sbv[4];
        #pragma unroll
        for (int ni = 0; ni < 4; ++ni)
            sbv[ni] = sb[bc * BN + wn + ni * 16 + mrow];
        #pragma unroll
        for (int mi = 0; mi < 4; ++mi) {
            #pragma unroll
            for (int r = 0; r < 4; ++r) {
                float v = fmaxf(fmaxf((float)acc[mi][0][r] * sbv[0],
                                      (float)acc[mi][1][r] * sbv[1]),
                                fmaxf((float)acc[mi][2][r] * sbv[2],
                                      (float)acc[mi][3][r] * sbv[3]));
                rm[mi][r] = fmaxf(rm[mi][r], v);
            }
        }
    }

    // single deferred epilogue: shfl-max over 16 cols, then *sa[row] (sa>0),
    // one atomic per (mi,r). C/D layout: col = lane&15, row = quad*4 + reg.
    #pragma unroll
    for (int mi = 0; mi < 4; ++mi) {
        #pragma unroll
        for (int r = 0; r < 4; ++r) {
            float v = rm[mi][r];
            v = fmaxf(v, __shfl_xor(v, 1));
            v = fmaxf(v, __shfl_xor(v, 2));
            v = fmaxf(v, __shfl_xor(v, 4));
            v = fmaxf(v, __shfl_xor(v, 8));
            if (mrow == 0) {
                const int row = row0 + mi * 16 + r;
                atomicMax(&out[row], enc_f(v * sa[row]));
            }
        }
    }
}

__global__ void decode_out_k(unsigned* __restrict__ u) {
    int i = blockIdx.x * 256 + threadIdx.x;
    ((float*)u)[i] = dec_f(u[i]);
}

extern "C" void kernel_launch(void* const* d_in, const int* in_sizes, int n_in,
                              void* d_out, int out_size, void* d_ws, size_t ws_size,
                              hipStream_t stream) {
    (void)in_sizes; (void)n_in; (void)out_size; (void)ws_size;
    const float* ex = (const float*)d_in[0];
    const float* ey = (const float*)d_in[1];
    // ws layout: qx[8192*768 B] ++ qy[8192*768 B] ++ scales[16384 f32]  (~12.6 MB)
    signed char* q = (signed char*)d_ws;
    float* scales  = (float*)(q + 2 * (size_t)NROWS * KDIM);
    unsigned* outu = (unsigned*)d_out;

    normalize_quant_k<<<(2 * NROWS) / 4, 256, 0, stream>>>(ex, ey, q, scales, outu);
    // grid: 64 br x 32 bcg = 2048 blocks = 5/CU (32 KB LDS each), 256 thr
    gemm_rowmax_i8_k<<<(NROWS / BM) * NBCG, 256, 0, stream>>>(
        q, q + (size_t)NROWS * KDIM, scales, scales + NROWS, outu);
    decode_out_k<<<NROWS / 256, 256, 0, stream>>>(outu);
}